// Round 6
// baseline (202.559 us; speedup 1.0000x reference)
//
#include <hip/hip_runtime.h>

#define OUT_SZ 299
#define PLANE (OUT_SZ * OUT_SZ)   // 89401
#define RPB 13                    // output rows per block: 13 * 23 = 299
#define CHUNKS 23

struct __align__(16) RowInfo {
    int   shift;   // 1 if the register window advances before this output row
    int   rowOff;  // element offset (within plane) of input row r1 (new hB)
    float wr;      // row frac weight
    float iwr;     // 1 - wr
};

__global__ __launch_bounds__(320) void crop_resize_kernel(
    const float* __restrict__ x,   // (32, 3, 299, 299)
    const int*   __restrict__ f,   // (32, 16, 4) = tlx, tly, brx, bry
    float*       __restrict__ out) // (32, 16, 3, 299, 299)
{
    __shared__ RowInfo rows[RPB];  // 208 B

    const int t     = threadIdx.x;   // output column (t < 299 active)
    const int chunk = blockIdx.x;    // 0..22
    const int c     = blockIdx.y;    // channel
    const int sg    = blockIdx.z;    // s*16 + g
    const int s     = sg >> 4;

    // Box is block-uniform -> scalar.
    const int4 box = *reinterpret_cast<const int4*>(f + (size_t)sg * 4);
    const int tlx = box.x, tly = box.y, brx = box.z, bry = box.w;
    const int hcI = brx - tlx, wcI = bry - tly;
    const float hc = (float)hcI, wc = (float)wcI;

    const int i0 = chunk * RPB;
    // First input row of this chunk's window (uniform).
    const float sr0 = fminf(fmaxf(((float)i0 + 0.5f) * hc / (float)OUT_SZ - 0.5f,
                                  0.0f), hc - 1.0f);
    const int rbase = (int)floorf(sr0);

    // Per-output-row table (block-uniform data).
    if (t < RPB) {
        const int i = i0 + t;
        float sr  = fminf(fmaxf(((float)i + 0.5f) * hc / (float)OUT_SZ - 0.5f,
                                0.0f), hc - 1.0f);
        float r0f = floorf(sr);
        int   r0  = (int)r0f;
        int   r1  = min(r0 + 1, hcI - 1);
        int   r0p = rbase;
        if (t > 0) {
            float srp = fminf(fmaxf(((float)(i - 1) + 0.5f) * hc / (float)OUT_SZ - 0.5f,
                                    0.0f), hc - 1.0f);
            r0p = (int)floorf(srp);
        }
        rows[t].shift  = r0 - r0p;              // 0 or 1
        rows[t].rowOff = (r1 + tlx) * OUT_SZ;   // element offset of new hB row
        float wr = sr - r0f;
        rows[t].wr  = wr;
        rows[t].iwr = 1.0f - wr;
    }

    // Per-column precompute: registers only.
    float sc  = fminf(fmaxf(((float)t + 0.5f) * wc / (float)OUT_SZ - 0.5f,
                            0.0f), wc - 1.0f);
    float c0f = floorf(sc);
    const int   c0   = (int)c0f + tly;
    const int   c1   = min((int)c0f + 1, wcI - 1) + tly;
    const float wcl  = sc - c0f;
    const float iwcl = 1.0f - wcl;

    const float* __restrict__ img = x + ((size_t)s * 3 + (size_t)c) * PLANE;
    const float* __restrict__ pc0 = img + c0;
    const float* __restrict__ pc1 = img + c1;

    // Init window: hA = h[r0[0]], hB = h[r1[0]] (clamped load handles edge).
    const int rowA = (rbase + tlx) * OUT_SZ;
    const int rowB = (min(rbase + 1, hcI - 1) + tlx) * OUT_SZ;
    float hA = pc0[rowA] * iwcl + pc1[rowA] * wcl;
    float hB = pc0[rowB] * iwcl + pc1[rowB] * wcl;

    __syncthreads();
    if (t >= OUT_SZ) return;

    float* __restrict__ orow = out + ((size_t)sg * 3 + (size_t)c) * PLANE
                             + (size_t)i0 * OUT_SZ + t;

    #pragma unroll
    for (int rr = 0; rr < RPB; ++rr) {
        const RowInfo ri = rows[rr];   // one broadcast ds_read_b128
        // Block-uniform flag -> scalar branch.
        if (__builtin_amdgcn_readfirstlane(ri.shift)) {
            hA = hB;
            const int ro = __builtin_amdgcn_readfirstlane(ri.rowOff);
            hB = pc0[ro] * iwcl + pc1[ro] * wcl;
        }
        orow[(size_t)rr * OUT_SZ] = hA * ri.iwr + hB * ri.wr;
    }
}

extern "C" void kernel_launch(void* const* d_in, const int* in_sizes, int n_in,
                              void* d_out, int out_size, void* d_ws, size_t ws_size,
                              hipStream_t stream) {
    const float* x   = (const float*)d_in[0];  // (32,3,299,299) fp32
    const int*   f   = (const int*)  d_in[1];  // (32,16,4) int32
    float*       out = (float*)d_out;          // (32,16,3,299,299) fp32

    dim3 grid(CHUNKS, 3, 32 * 16);
    crop_resize_kernel<<<grid, 320, 0, stream>>>(x, f, out);
}

// Round 7
// 173.669 us; speedup vs baseline: 1.1663x; 1.1663x over previous
//
#include <hip/hip_runtime.h>

#define OUT_SZ 299
#define PLANE (OUT_SZ * OUT_SZ)   // 89401
#define RPB 13                    // output rows per block: 13 * 23 = 299
#define CHUNKS 23

__global__ __launch_bounds__(320) void crop_resize_kernel(
    const float* __restrict__ x,   // (32, 3, 299, 299)
    const int*   __restrict__ f,   // (32, 16, 4) = tlx, tly, brx, bry
    float*       __restrict__ out) // (32, 16, 3, 299, 299)
{
    const int t     = threadIdx.x;   // output column
    const int chunk = blockIdx.x;    // 0..22
    const int c     = blockIdx.y;    // channel
    const int sg    = blockIdx.z;    // s*16 + g
    const int s     = sg >> 4;

    if (t >= OUT_SZ) return;         // no LDS, no barriers -> safe

    // Box is block-uniform -> scalar loads.
    const int4 box = *reinterpret_cast<const int4*>(f + (size_t)sg * 4);
    const int tlx = box.x, tly = box.y, brx = box.z, bry = box.w;
    const int hcI = brx - tlx, wcI = bry - tly;
    const float hc = (float)hcI, wc = (float)wcI;

    // Per-column precompute (registers only).
    float sc  = fminf(fmaxf(((float)t + 0.5f) * wc / (float)OUT_SZ - 0.5f,
                            0.0f), wc - 1.0f);
    float c0f = floorf(sc);
    const int   c0  = (int)c0f + tly;
    const int   c1  = min((int)c0f + 1, wcI - 1) + tly;
    const float wcl = sc - c0f;

    const float* __restrict__ img = x + ((size_t)s * 3 + (size_t)c) * PLANE;

    const int   i0     = chunk * RPB;
    const float rscale = hc / (float)OUT_SZ;
    const float rbias  = 0.5f * rscale - 0.5f;
    const float rmax   = hc - 1.0f;

    // Init window: hA = h[r0(row i0)]; hB unused until first shift (never at rr=0).
    float sr0 = fminf(fmaxf((float)i0 * rscale + rbias, 0.0f), rmax);
    int   r0p = (int)floorf(sr0);
    {
        const int ra = (r0p + tlx) * OUT_SZ;
        float a0 = img[ra + c0], a1 = img[ra + c1];
        // fall through: hA computed below
        sr0 = a0 + wcl * (a1 - a0);   // reuse sr0 reg as hA seed
    }
    float hA = sr0;
    float hB = hA;   // placeholder; overwritten at rr=0 before any use via shift

    float* __restrict__ orow = out + ((size_t)sg * 3 + (size_t)c) * PLANE
                             + (size_t)i0 * OUT_SZ + t;

    #pragma unroll
    for (int rr = 0; rr < RPB; ++rr) {
        // Row math: ~8 VALU ops, block-uniform values, no memory dependence.
        float sr  = fminf(fmaxf((float)(i0 + rr) * rscale + rbias, 0.0f), rmax);
        float r0f = floorf(sr);
        int   r0  = (int)r0f;
        float wr  = sr - r0f;
        int   r1  = min(r0 + 1, hcI - 1);
        int   ro  = (r1 + tlx) * OUT_SZ;

        // Fresh load of h[r1] every row (L1-hit when window didn't move).
        float v0 = img[ro + c0], v1 = img[ro + c1];
        float hN = v0 + wcl * (v1 - v0);

        // Branchless window advance: if r0 stepped, old hB == h[new r0].
        hA  = (r0 != r0p) ? hB : hA;
        hB  = hN;
        r0p = r0;

        orow[(size_t)rr * OUT_SZ] = hA + wr * (hB - hA);
    }
}

extern "C" void kernel_launch(void* const* d_in, const int* in_sizes, int n_in,
                              void* d_out, int out_size, void* d_ws, size_t ws_size,
                              hipStream_t stream) {
    const float* x   = (const float*)d_in[0];  // (32,3,299,299) fp32
    const int*   f   = (const int*)  d_in[1];  // (32,16,4) int32
    float*       out = (float*)d_out;          // (32,16,3,299,299) fp32

    dim3 grid(CHUNKS, 3, 32 * 16);
    crop_resize_kernel<<<grid, 320, 0, stream>>>(x, f, out);
}

// Round 8
// 149.983 us; speedup vs baseline: 1.3505x; 1.1579x over previous
//
#include <hip/hip_runtime.h>

#define OUT_SZ 299
#define PLANE (OUT_SZ * OUT_SZ)   // 89401
#define RPB 13                    // output rows per block: 13 * 23 = 299
#define CHUNKS 23
#define NSLOT 10                  // h slots: s0 in [0,8], hB slot = s0+1 <= 9
#define HSTRIDE 11                // odd stride -> 2-way bank aliasing only (free)

__global__ __launch_bounds__(320) void crop_resize_kernel(
    const float* __restrict__ x,   // (32, 3, 299, 299)
    const int*   __restrict__ f,   // (32, 16, 4) = tlx, tly, brx, bry
    float*       __restrict__ out) // (32, 16, 3, 299, 299)
{
    __shared__ float h[OUT_SZ * HSTRIDE];   // 13156 B, transposed: h[col*11+slot]

    const int t     = threadIdx.x;   // output column
    const int chunk = blockIdx.x;    // 0..22
    const int c     = blockIdx.y;    // channel
    const int sg    = blockIdx.z;    // s*16 + g
    const int s     = sg >> 4;

    // Box is block-uniform -> scalar loads.
    const int4 box = *reinterpret_cast<const int4*>(f + (size_t)sg * 4);
    const int tlx = box.x, tly = box.y, brx = box.z, bry = box.w;
    const int hcI = brx - tlx, wcI = bry - tly;
    const float hc = (float)hcI, wc = (float)wcI;

    const int   i0     = chunk * RPB;
    const float rscale = hc / (float)OUT_SZ;
    const float rbias  = 0.5f * rscale - 0.5f;
    const float rmax   = hc - 1.0f;

    const float sr0 = fminf(fmaxf((float)i0 * rscale + rbias, 0.0f), rmax);
    const int rbase = (int)floorf(sr0);

    // Per-row table in lanes 0..12 of EVERY wave (registers, no LDS):
    // lane rr holds (slot index s0, row weight wr) for output row i0+rr.
    const int lane = t & 63;
    int   s0v;
    float wrv;
    {
        float sr  = fminf(fmaxf((float)(i0 + lane) * rscale + rbias, 0.0f), rmax);
        float r0f = floorf(sr);
        wrv = sr - r0f;
        s0v = min(max((int)r0f - rbase, 0), NSLOT - 2);  // proven in [0,8]; clamp = insurance
    }

    // Per-column precompute (registers only).
    float sc  = fminf(fmaxf(((float)t + 0.5f) * wc / (float)OUT_SZ - 0.5f,
                            0.0f), wc - 1.0f);
    float c0f = floorf(sc);
    const int   c0  = (int)c0f + tly;
    const int   c1  = min((int)c0f + 1, wcI - 1) + tly;
    const float wcl = sc - c0f;

    const float* __restrict__ img = x + ((size_t)s * 3 + (size_t)c) * PLANE;

    // Phase 1: col-interp each needed input row once -> transposed h.
    if (t < OUT_SZ) {
        #pragma unroll
        for (int r = 0; r < NSLOT; ++r) {
            const int rl = min(rbase + r, hcI - 1) + tlx;   // clamped input row
            const float* p = img + (size_t)rl * OUT_SZ;
            float v0 = p[c0], v1 = p[c1];
            h[t * HSTRIDE + r] = v0 + wcl * (v1 - v0);
        }
    }
    __syncthreads();
    if (t >= OUT_SZ) return;

    float* __restrict__ orow = out + ((size_t)sg * 3 + (size_t)c) * PLANE
                             + (size_t)i0 * OUT_SZ + t;
    const float* __restrict__ hT = h + t * HSTRIDE;

    // Phase 2: per row = 1 ds_read2_b32 + 2 FMA + 1 coalesced store.
    #pragma unroll
    for (int rr = 0; rr < RPB; ++rr) {
        const int   s0 = __builtin_amdgcn_readlane(s0v, rr);
        const float wr = __int_as_float(
                             __builtin_amdgcn_readlane(__float_as_int(wrv), rr));
        float hA = hT[s0];
        float hB = hT[s0 + 1];   // adjacent dword -> ds_read2_b32 with hA
        orow[(size_t)rr * OUT_SZ] = hA + wr * (hB - hA);
    }
}

extern "C" void kernel_launch(void* const* d_in, const int* in_sizes, int n_in,
                              void* d_out, int out_size, void* d_ws, size_t ws_size,
                              hipStream_t stream) {
    const float* x   = (const float*)d_in[0];  // (32,3,299,299) fp32
    const int*   f   = (const int*)  d_in[1];  // (32,16,4) int32
    float*       out = (float*)d_out;          // (32,16,3,299,299) fp32

    dim3 grid(CHUNKS, 3, 32 * 16);
    crop_resize_kernel<<<grid, 320, 0, stream>>>(x, f, out);
}

// Round 10
// 138.535 us; speedup vs baseline: 1.4621x; 1.0826x over previous
//
#include <hip/hip_runtime.h>

#define OUT_SZ 299
#define PLANE (OUT_SZ * OUT_SZ)   // 89401
#define RPB 13                    // output rows per block: 13 * 23 = 299
#define CHUNKS 23
#define TSTRIDE 201               // tmp row stride in dwords (odd; >= wcI+1, wcI<=199)

__global__ __launch_bounds__(320) void crop_resize_kernel(
    const float* __restrict__ x,   // (32, 3, 299, 299)
    const int*   __restrict__ f,   // (32, 16, 4) = tlx, tly, brx, bry
    float*       __restrict__ out) // (32, 16, 3, 299, 299)
{
    __shared__ float tmp[RPB * TSTRIDE];   // 10452 B: row-interped crop rows

    const int t     = threadIdx.x;
    const int chunk = blockIdx.x;    // 0..22
    const int c     = blockIdx.y;    // channel
    const int sg    = blockIdx.z;    // s*16 + g
    const int s     = sg >> 4;

    // Box is block-uniform -> scalar loads.
    const int4 box = *reinterpret_cast<const int4*>(f + (size_t)sg * 4);
    const int tlx = box.x, tly = box.y, brx = box.z, bry = box.w;
    const int hcI = brx - tlx, wcI = bry - tly;
    const float hc = (float)hcI, wc = (float)wcI;

    const int i0 = chunk * RPB;

    // Lane-table values: lanes 0..12 of EVERY wave hold row info for row i0+rr.
    // Computed by ALL threads (uniform control flow).
    const int lane = t & 63;
    int v_r0e, v_r1e;
    float v_wr;
    {
        float sr  = fminf(fmaxf(((float)(i0 + lane) + 0.5f) * hc / (float)OUT_SZ
                                - 0.5f, 0.0f), hc - 1.0f);
        float r0f = floorf(sr);
        v_wr = sr - r0f;
        int r0l = (int)r0f;
        int r1l = min(r0l + 1, hcI - 1);
        v_r0e = (r0l + tlx) * OUT_SZ + tly;
        v_r1e = (r1l + tlx) * OUT_SZ + tly;
    }

    // Hoist ALL readlanes into uniform control flow (convergent-op safety):
    // results are wave-uniform scalars, statically indexed -> SGPRs.
    int   sr0e[RPB], sr1e[RPB];
    float srw[RPB];
    #pragma unroll
    for (int rr = 0; rr < RPB; ++rr) {
        sr0e[rr] = __builtin_amdgcn_readlane(v_r0e, rr);
        sr1e[rr] = __builtin_amdgcn_readlane(v_r1e, rr);
        srw[rr]  = __int_as_float(
                       __builtin_amdgcn_readlane(__float_as_int(v_wr), rr));
    }

    // Per-output-column precompute (registers only). c0 is CROP-LOCAL.
    float sc  = fminf(fmaxf(((float)t + 0.5f) * wc / (float)OUT_SZ - 0.5f,
                            0.0f), wc - 1.0f);
    float c0f = floorf(sc);
    const int   c0  = (int)c0f;          // in [0, wcI-1]
    const float wcl = sc - c0f;

    const float* __restrict__ img = x + ((size_t)s * 3 + (size_t)c) * PLANE;

    // Phase 1: vertical (row) interp over crop columns — COALESCED loads.
    // Thread t handles input col t; t == wcI writes the duplicate pad col.
    if (t <= wcI) {                      // plain loads/stores only inside
        const int jl = min(t, wcI - 1);
        #pragma unroll
        for (int rr = 0; rr < RPB; ++rr) {
            float a = img[sr0e[rr] + jl];    // uniform base + lane index
            float b = img[sr1e[rr] + jl];
            tmp[rr * TSTRIDE + t] = a + srw[rr] * (b - a);
        }
    }
    __syncthreads();
    if (t >= OUT_SZ) return;

    // Phase 2: horizontal (col) interp — 1 ds_read2_b32 + 2 FMA + store per px.
    float* __restrict__ orow = out + ((size_t)sg * 3 + (size_t)c) * PLANE
                             + (size_t)i0 * OUT_SZ + t;
    #pragma unroll
    for (int rr = 0; rr < RPB; ++rr) {
        const float* p = tmp + rr * TSTRIDE + c0;
        float hA = p[0];
        float hB = p[1];   // adjacent dword; pad col makes the c1-clamp exact
        orow[(size_t)rr * OUT_SZ] = hA + wcl * (hB - hA);
    }
}

extern "C" void kernel_launch(void* const* d_in, const int* in_sizes, int n_in,
                              void* d_out, int out_size, void* d_ws, size_t ws_size,
                              hipStream_t stream) {
    const float* x   = (const float*)d_in[0];  // (32,3,299,299) fp32
    const int*   f   = (const int*)  d_in[1];  // (32,16,4) int32
    float*       out = (float*)d_out;          // (32,16,3,299,299) fp32

    dim3 grid(CHUNKS, 3, 32 * 16);
    crop_resize_kernel<<<grid, 320, 0, stream>>>(x, f, out);
}